// Round 3
// baseline (407.647 us; speedup 1.0000x reference)
//
#include <hip/hip_runtime.h>
#include <hip/hip_bf16.h>

#define BB 2
#define TT 2048
#define DD 2048
#define HH 16
#define HDIM 128
#define BT 4096   // B*T
#define N3 6144   // 3*D

typedef __attribute__((ext_vector_type(8))) short s16x8;
typedef __attribute__((ext_vector_type(4))) float f32x4;

static __device__ __forceinline__ ushort f2bf(float x) {
  union { float f; unsigned u; } cv; cv.f = x;
  unsigned r = cv.u + 0x7FFF + ((cv.u >> 16) & 1);   // RNE
  return (ushort)(r >> 16);
}
static __device__ __forceinline__ float bf2f(ushort u) {
  union { unsigned u; float f; } cv; cv.u = ((unsigned)u) << 16; return cv.f;
}

#define GLDS16(gp, lp) __builtin_amdgcn_global_load_lds( \
    (const __attribute__((address_space(1))) void*)(gp), \
    (__attribute__((address_space(3))) void*)(lp), 16, 0, 0)

// ---------------- f32 -> bf16 convert (vectorized) ----------------
__global__ void cvt_kernel(const float* __restrict__ in, ushort* __restrict__ out, int n4) {
  int i = blockIdx.x * blockDim.x + threadIdx.x;
  if (i < n4) {
    float4 v = ((const float4*)in)[i];
    ushort4 o;
    o.x = f2bf(v.x); o.y = f2bf(v.y); o.z = f2bf(v.z); o.w = f2bf(v.w);
    ((ushort4*)out)[i] = o;
  }
}

// ---------------- tiled transpose + convert: in[R][C] f32 -> out[C][R] bf16 ----------------
__global__ void transpose_cvt(const float* __restrict__ in, ushort* __restrict__ out, int R, int C) {
  __shared__ float tile[32][33];
  const int bx = blockIdx.x * 32, by = blockIdx.y * 32;
  const int tx = threadIdx.x, ty = threadIdx.y;   // 32 x 8
  #pragma unroll
  for (int i = 0; i < 32; i += 8)
    tile[ty + i][tx] = in[(size_t)(by + ty + i) * C + bx + tx];
  __syncthreads();
  #pragma unroll
  for (int i = 0; i < 32; i += 8)
    out[(size_t)(bx + ty + i) * R + by + tx] = f2bf(tile[tx][ty + i]);
}

// ================= 256x256 8-phase QKV GEMM, v2 =================
// m201 geometry: LDS per (buf, matrix) = [256 rows][64 bf16] (128B rows),
// swizzle colb ^= ((row>>2)&1)<<5 (measured conflict-free, m201).
// Schedule (race-free by retirement analysis):
//   phase0: stage B(T+1) -> other buf (B region retired at T-1 p3 barrier)
//   phase3: stage A(T+2) -> same buf  (A region retired at T   p2 barrier)
//   vmcnt(4) once per tile at p3 (leaves only the just-issued A-stage in flight);
//   vmcnt(0) for the last two tiles.
__global__ __launch_bounds__(512, 1)
void gemm8_qkv(const ushort* __restrict__ A, const ushort* __restrict__ Bt,
               ushort* __restrict__ Qb, ushort* __restrict__ Kb, ushort* __restrict__ Vb)
{
  constexpr int K = 2048;
  constexpr int NT = K / 64;     // 32 K-tiles
  __shared__ char smem[131072];  // buf<<16 | mat<<15 ; [256][64] bf16 swizzled

  const int tid = threadIdx.x, wave = tid >> 6, lane = tid & 63;
  const int lr = lane & 15, lg = lane >> 4;
  const int wm = wave >> 2, wn = wave & 3;

  // XCD-aware 8x6 chunking: xcd = wg&7 owns an 8-row x 6-col tile chunk,
  // swept column-major (A chunk 8MB + B panel reuse within L2).
  const int wg = blockIdx.x;            // 0..383
  const int xcd = wg & 7, l = wg >> 3;  // l in 0..47
  const int rgrp = xcd >> 2, cgrp = xcd & 3;
  const int lrow = l & 7, lcol = l >> 3;
  const int by = rgrp * 8 + lrow, bx = cgrp * 6 + lcol;
  const int m0 = by * 256, n0 = bx * 256;

  // stage one full 256x64 matrix tile (4 x global_load_lds per thread)
  auto stage2 = [&](const ushort* src, int base0, int U, char* region) {
    #pragma unroll
    for (int inst = 0; inst < 4; ++inst) {
      const int c = inst * 512 + tid;          // 16B chunk, lds off = c*16
      const int row = c >> 3;                  // 0..255
      const int colb = (c & 7) * 16;           // 0..112
      const int colsw = colb ^ (((row >> 2) & 1) << 5);  // inverse-swizzled SOURCE
      const ushort* gp = src + (size_t)(base0 + row) * K + U * 64 + (colsw >> 1);
      GLDS16(gp, region + inst * 8192 + wave * 1024);
    }
  };

  f32x4 acc[8][4] = {};

  // prologue: A(0), B(0), A(1); wait A0+B0 landed (A1 stays in flight)
  stage2(A,  m0, 0, smem);
  stage2(Bt, n0, 0, smem + 32768);
  stage2(A,  m0, 1, smem + 65536);
  asm volatile("s_waitcnt vmcnt(4)" ::: "memory");
  __builtin_amdgcn_s_barrier();

  for (int T = 0; T < NT; ++T) {
    const int buf = T & 1;
    char* Ab = smem + (buf << 16);
    char* Bb = smem + (buf << 16) + 32768;
    s16x8 a[8];
    #pragma unroll
    for (int p = 0; p < 4; ++p) {
      const int kk = p >> 1, qn = p & 1;
      if ((p & 1) == 0) {
        #pragma unroll
        for (int mf = 0; mf < 8; ++mf) {
          const int r = wm * 128 + mf * 16 + lr;
          a[mf] = *(const s16x8*)(Ab + r * 128 + ((kk * 64 + lg * 16) ^ (((r >> 2) & 1) << 5)));
        }
      }
      s16x8 b[2];
      #pragma unroll
      for (int nf = 0; nf < 2; ++nf) {
        const int r = wn * 64 + (qn * 2 + nf) * 16 + lr;
        b[nf] = *(const s16x8*)(Bb + r * 128 + ((kk * 64 + lg * 16) ^ (((r >> 2) & 1) << 5)));
      }
      if (p == 0 && T + 1 < NT) stage2(Bt, n0, T + 1, smem + (((T + 1) & 1) << 16) + 32768);
      if (p == 3 && T + 2 < NT) stage2(A,  m0, T + 2, smem + ((buf) << 16));  // (T+2)&1 == buf
      __builtin_amdgcn_s_barrier();
      asm volatile("s_waitcnt lgkmcnt(0)" ::: "memory");
      __builtin_amdgcn_sched_barrier(0);
      __builtin_amdgcn_s_setprio(1);
      #pragma unroll
      for (int mf = 0; mf < 8; ++mf)
        #pragma unroll
        for (int nf = 0; nf < 2; ++nf)
          acc[mf][qn * 2 + nf] =
            __builtin_amdgcn_mfma_f32_16x16x32_bf16(a[mf], b[nf], acc[mf][qn * 2 + nf], 0, 0, 0);
      __builtin_amdgcn_s_setprio(0);
      if (p == 3) {
        if (T < NT - 2) { asm volatile("s_waitcnt vmcnt(4)" ::: "memory"); }
        else            { asm volatile("s_waitcnt vmcnt(0)" ::: "memory"); }
      }
      __builtin_amdgcn_s_barrier();
    }
  }

  // epilogue: scatter bf16 into per-head Q/K/V [B,H,T,HD]
  #pragma unroll
  for (int mf = 0; mf < 8; ++mf) {
    #pragma unroll
    for (int nn = 0; nn < 4; ++nn) {
      #pragma unroll
      for (int r = 0; r < 4; ++r) {
        const int rowg = m0 + wm * 128 + mf * 16 + lg * 4 + r;
        const int colg = n0 + wn * 64 + nn * 16 + lr;
        const int which = colg >> 11, rem = colg & 2047;
        const int hh = rem >> 7, d = rem & 127;
        const int b2 = rowg >> 11, t = rowg & 2047;
        ushort* dstp = (which == 0) ? Qb : (which == 1) ? Kb : Vb;
        dstp[(((size_t)b2 * HH + hh) * TT + t) * HDIM + d] = f2bf(acc[mf][nn][r]);
      }
    }
  }
}

// ---------------- m97-style GEMM kept for the out-projection ----------------
__global__ __launch_bounds__(256, 2)
void gemm_bt2(const ushort* __restrict__ A, const ushort* __restrict__ Bt,
              float* __restrict__ Cf, int M, int N, int K)
{
  __shared__ ushort As[128 * 32];
  __shared__ ushort Bs[128 * 32];
  const int tid = threadIdx.x;
  const int wave = tid >> 6, lane = tid & 63;
  const int lr = lane & 15, lg = lane >> 4;
  const int m0 = blockIdx.y * 128, n0 = blockIdx.x * 128;
  const int wm = (wave & 1) * 64, wn = (wave >> 1) * 64;
  f32x4 acc[4][4] = {};

  for (int k0 = 0; k0 < K; k0 += 32) {
    __syncthreads();
    #pragma unroll
    for (int call = 0; call < 2; ++call) {
      const int base = call * 256 + wave * 64;
      const int c = base + lane;
      const int row = c >> 2, cc = c & 3;
      GLDS16(A  + (size_t)(m0 + row) * K + k0 + cc * 8, As + (size_t)base * 8);
      GLDS16(Bt + (size_t)(n0 + row) * K + k0 + cc * 8, Bs + (size_t)base * 8);
    }
    __syncthreads();
    s16x8 a[4], b[4];
    #pragma unroll
    for (int i = 0; i < 4; ++i) a[i] = *(const s16x8*)&As[(wm + i * 16 + lr) * 32 + lg * 8];
    #pragma unroll
    for (int i = 0; i < 4; ++i) b[i] = *(const s16x8*)&Bs[(wn + i * 16 + lr) * 32 + lg * 8];
    #pragma unroll
    for (int mi = 0; mi < 4; ++mi)
      #pragma unroll
      for (int ni = 0; ni < 4; ++ni)
        acc[mi][ni] = __builtin_amdgcn_mfma_f32_16x16x32_bf16(a[mi], b[ni], acc[mi][ni], 0, 0, 0);
  }

  #pragma unroll
  for (int mi = 0; mi < 4; ++mi)
    #pragma unroll
    for (int ni = 0; ni < 4; ++ni)
      #pragma unroll
      for (int r = 0; r < 4; ++r) {
        const int row = m0 + wm + mi * 16 + lg * 4 + r;
        const int col = n0 + wn + ni * 16 + lr;
        Cf[(size_t)row * N + col] = acc[mi][ni][r];
      }
}

// ---------------- in-place RoPE on Q and K ([B,H,T,HD] bf16) ----------------
__global__ void rope_inplace(ushort* __restrict__ Qb, ushort* __restrict__ Kb,
                             const float* __restrict__ sinp, const float* __restrict__ cosp) {
  const int idx = blockIdx.x * 256 + threadIdx.x;   // B*H*T*64 threads
  const int d = idx & 63;
  const int t = (idx >> 6) & (TT - 1);
  const int bh = idx >> 17;
  const float c = cosp[t * HDIM + d];
  const float s = sinp[t * HDIM + d];
  const size_t base = ((size_t)bh * TT + t) * HDIM + d;
  float q1 = bf2f(Qb[base]), q2 = bf2f(Qb[base + 64]);
  Qb[base]      = f2bf(q1 * c - q2 * s);
  Qb[base + 64] = f2bf(q2 * c + q1 * s);
  float k1 = bf2f(Kb[base]), k2 = bf2f(Kb[base + 64]);
  Kb[base]      = f2bf(k1 * c - k2 * s);
  Kb[base + 64] = f2bf(k2 * c + k1 * s);
}

// ---------------- flash attention with causal + same-doc mask ----------------
__global__ __launch_bounds__(256, 2)
void attn_kernel(const ushort* __restrict__ Qb, const ushort* __restrict__ Kb,
                 const ushort* __restrict__ Vb, const int* __restrict__ doc,
                 ushort* __restrict__ Ob)
{
  __shared__ ushort Ks[64 * 128];    // K tile, XOR-swizzled rows
  __shared__ ushort VTs[128 * 64];   // V^T tile, XOR-swizzled rows
  __shared__ ushort Ps[4][16 * 64];  // per-wave P tile, XOR-swizzled rows
  const int qt = blockIdx.x, h = blockIdx.y, b = blockIdx.z;
  const int q0 = qt * 64;
  const int tid = threadIdx.x, wave = tid >> 6, lane = tid & 63;
  const int lr = lane & 15, lg = lane >> 4;
  const size_t bh = (size_t)b * HH + h;
  const int* docb = doc + b * TT;

  const ushort* Qp = Qb + (bh * TT + q0 + wave * 16) * HDIM;
  s16x8 aq[4];
  #pragma unroll
  for (int ks = 0; ks < 4; ++ks) aq[ks] = *(const s16x8*)&Qp[lr * HDIM + ks * 32 + lg * 8];

  int qdoc[4];
  #pragma unroll
  for (int r = 0; r < 4; ++r) qdoc[r] = docb[q0 + wave * 16 + lg * 4 + r];
  const int qdoc0 = docb[q0];

  float m2[4], lsum[4];
  #pragma unroll
  for (int r = 0; r < 4; ++r) { m2[r] = -1e30f; lsum[r] = 0.f; }
  f32x4 oacc[8] = {};

  const float sc = 0.08838834764831843f * 1.4426950408889634f;  // 1/sqrt(128) * log2(e)

  const ushort* Kbase = Kb + bh * TT * HDIM;
  const ushort* Vbase = Vb + bh * TT * HDIM;

  const int ntiles = qt + 1;
  for (int kt = 0; kt < ntiles; ++kt) {
    const int kv0 = kt * 64;
    if (docb[kv0 + 63] < qdoc0) continue;
    __syncthreads();
    #pragma unroll
    for (int i = 0; i < 4; ++i) {
      const int c = tid + i * 256;
      const int row = c >> 4, c8 = c & 15;
      s16x8 v = *(const s16x8*)&Kbase[(size_t)(kv0 + row) * HDIM + c8 * 8];
      const int off = (row * 256 + c8 * 16) ^ ((row & 7) << 4);
      *(s16x8*)((char*)Ks + off) = v;
    }
    #pragma unroll
    for (int i = 0; i < 4; ++i) {
      const int c = tid + i * 256;
      const int kv = c >> 4, d8 = c & 15;
      s16x8 v = *(const s16x8*)&Vbase[(size_t)(kv0 + kv) * HDIM + d8 * 8];
      #pragma unroll
      for (int j = 0; j < 8; ++j) {
        const int d = d8 * 8 + j;
        const int off = (d * 128 + kv * 2) ^ ((d & 7) << 4);
        *(ushort*)((char*)VTs + off) = (ushort)v[j];
      }
    }
    __syncthreads();

    f32x4 sfrag[4] = {};
    #pragma unroll
    for (int ks = 0; ks < 4; ++ks) {
      #pragma unroll
      for (int ct = 0; ct < 4; ++ct) {
        const int row = ct * 16 + lr;
        const int off = (row * 256 + ks * 64 + lg * 16) ^ ((row & 7) << 4);
        s16x8 bk = *(const s16x8*)((char*)Ks + off);
        sfrag[ct] = __builtin_amdgcn_mfma_f32_16x16x32_bf16(aq[ks], bk, sfrag[ct], 0, 0, 0);
      }
    }

    int kd[4];
    #pragma unroll
    for (int ct = 0; ct < 4; ++ct) kd[ct] = docb[kv0 + ct * 16 + lr];

    float s[4][4], tmax[4];
    #pragma unroll
    for (int r = 0; r < 4; ++r) tmax[r] = -1e30f;
    #pragma unroll
    for (int ct = 0; ct < 4; ++ct) {
      const int col = kv0 + ct * 16 + lr;
      #pragma unroll
      for (int r = 0; r < 4; ++r) {
        const int row = q0 + wave * 16 + lg * 4 + r;
        float v = sfrag[ct][r] * sc;
        const bool keep = (col <= row) && (kd[ct] == qdoc[r]);
        v = keep ? v : -1e30f;
        s[ct][r] = v;
        tmax[r] = fmaxf(tmax[r], v);
      }
    }
    #pragma unroll
    for (int r = 0; r < 4; ++r) {
      #pragma unroll
      for (int off = 8; off >= 1; off >>= 1)
        tmax[r] = fmaxf(tmax[r], __shfl_xor(tmax[r], off, 16));
    }
    float alpha[4];
    #pragma unroll
    for (int r = 0; r < 4; ++r) {
      const float mnew = fmaxf(m2[r], tmax[r]);
      alpha[r] = exp2f(m2[r] - mnew);
      m2[r] = mnew;
      lsum[r] *= alpha[r];
    }
    #pragma unroll
    for (int ct = 0; ct < 4; ++ct) {
      #pragma unroll
      for (int r = 0; r < 4; ++r) {
        const float p = (s[ct][r] > -1e29f) ? exp2f(s[ct][r] - m2[r]) : 0.f;
        lsum[r] += p;
        const int prow = lg * 4 + r;
        const int off = (prow * 128 + (ct * 16 + lr) * 2) ^ ((prow & 7) << 4);
        *(ushort*)((char*)&Ps[wave][0] + off) = f2bf(p);
      }
    }
    #pragma unroll
    for (int oc = 0; oc < 8; ++oc)
      #pragma unroll
      for (int r = 0; r < 4; ++r) oacc[oc][r] *= alpha[r];
    #pragma unroll
    for (int ks = 0; ks < 2; ++ks) {
      const int poff = (lr * 128 + ks * 64 + lg * 16) ^ ((lr & 7) << 4);
      s16x8 ap = *(const s16x8*)((char*)&Ps[wave][0] + poff);
      #pragma unroll
      for (int oc = 0; oc < 8; ++oc) {
        const int vrow = oc * 16 + lr;
        const int voff = (vrow * 128 + ks * 64 + lg * 16) ^ ((vrow & 7) << 4);
        s16x8 bv = *(const s16x8*)((char*)VTs + voff);
        oacc[oc] = __builtin_amdgcn_mfma_f32_16x16x32_bf16(ap, bv, oacc[oc], 0, 0, 0);
      }
    }
  }

  #pragma unroll
  for (int r = 0; r < 4; ++r)
    #pragma unroll
    for (int off = 8; off >= 1; off >>= 1)
      lsum[r] += __shfl_xor(lsum[r], off, 16);

  ushort* Op = Ob + ((size_t)b * TT + q0 + wave * 16) * DD + (size_t)h * HDIM;
  #pragma unroll
  for (int oc = 0; oc < 8; ++oc)
    #pragma unroll
    for (int r = 0; r < 4; ++r)
      Op[(lg * 4 + r) * DD + oc * 16 + lr] = f2bf(oacc[oc][r] / lsum[r]);
}

extern "C" void kernel_launch(void* const* d_in, const int* in_sizes, int n_in,
                              void* d_out, int out_size, void* d_ws, size_t ws_size,
                              hipStream_t stream)
{
  const float* x    = (const float*)d_in[0];
  const float* sinp = (const float*)d_in[1];
  const float* cosp = (const float*)d_in[2];
  const float* Wqkv = (const float*)d_in[3];
  const float* Wout = (const float*)d_in[4];
  const int*   doc  = (const int*)d_in[5];
  float* out = (float*)d_out;

  ushort* xb  = (ushort*)d_ws;                     // 4096*2048 bf16
  ushort* WqT = xb  + (size_t)BT * DD;             // 6144*2048
  ushort* WoT = WqT + (size_t)N3 * DD;             // 2048*2048
  ushort* Qb  = WoT + (size_t)DD * DD;             // [B,H,T,HD]
  ushort* Kb  = Qb  + (size_t)BB * TT * DD;
  ushort* Vb  = Kb  + (size_t)BB * TT * DD;
  ushort* Ob  = Vb  + (size_t)BB * TT * DD;        // [B,T,D]

  cvt_kernel<<<(BT * DD / 4 + 255) / 256, 256, 0, stream>>>(x, xb, BT * DD / 4);
  transpose_cvt<<<dim3(N3 / 32, DD / 32), dim3(32, 8), 0, stream>>>(Wqkv, WqT, DD, N3);
  transpose_cvt<<<dim3(DD / 32, DD / 32), dim3(32, 8), 0, stream>>>(Wout, WoT, DD, DD);
  gemm8_qkv<<<dim3((N3 / 256) * (BT / 256)), 512, 0, stream>>>(xb, WqT, Qb, Kb, Vb);
  rope_inplace<<<BB * HH * TT * 64 / 256, 256, 0, stream>>>(Qb, Kb, sinp, cosp);
  attn_kernel<<<dim3(TT / 64, HH, BB), 256, 0, stream>>>(Qb, Kb, Vb, doc, Ob);
  gemm_bt2<<<dim3(DD / 128, BT / 128), 256, 0, stream>>>(Ob, WoT, out, BT, DD, DD);
}

// Round 8
// 393.552 us; speedup vs baseline: 1.0358x; 1.0358x over previous
//
#include <hip/hip_runtime.h>
#include <hip/hip_bf16.h>

#define BB 2
#define TT 2048
#define DD 2048
#define HH 16
#define HDIM 128
#define BT 4096   // B*T
#define N3 6144   // 3*D

typedef __attribute__((ext_vector_type(8))) short s16x8;
typedef __attribute__((ext_vector_type(4))) float f32x4;

static __device__ __forceinline__ ushort f2bf(float x) {
  union { float f; unsigned u; } cv; cv.f = x;
  unsigned r = cv.u + 0x7FFF + ((cv.u >> 16) & 1);   // RNE
  return (ushort)(r >> 16);
}
static __device__ __forceinline__ float bf2f(ushort u) {
  union { unsigned u; float f; } cv; cv.u = ((unsigned)u) << 16; return cv.f;
}

#define GLDS16(gp, lp) __builtin_amdgcn_global_load_lds( \
    (const __attribute__((address_space(1))) void*)(gp), \
    (__attribute__((address_space(3))) void*)(lp), 16, 0, 0)

// ---------------- f32 -> bf16 convert (vectorized) ----------------
__global__ void cvt_kernel(const float* __restrict__ in, ushort* __restrict__ out, int n4) {
  int i = blockIdx.x * blockDim.x + threadIdx.x;
  if (i < n4) {
    float4 v = ((const float4*)in)[i];
    ushort4 o;
    o.x = f2bf(v.x); o.y = f2bf(v.y); o.z = f2bf(v.z); o.w = f2bf(v.w);
    ((ushort4*)out)[i] = o;
  }
}

// ---------------- tiled transpose + convert: in[R][C] f32 -> out[C][R] bf16 ----------------
__global__ void transpose_cvt(const float* __restrict__ in, ushort* __restrict__ out, int R, int C) {
  __shared__ float tile[32][33];
  const int bx = blockIdx.x * 32, by = blockIdx.y * 32;
  const int tx = threadIdx.x, ty = threadIdx.y;   // 32 x 8
  #pragma unroll
  for (int i = 0; i < 32; i += 8)
    tile[ty + i][tx] = in[(size_t)(by + ty + i) * C + bx + tx];
  __syncthreads();
  #pragma unroll
  for (int i = 0; i < 32; i += 8)
    out[(size_t)(bx + ty + i) * R + by + tx] = f2bf(tile[tx][ty + i]);
}

// ================= 256x256 QKV GEMM, v3: barrier-light =================
// One barrier per K-tile. Reads hit buf, stage(T+1) writes buf^1 (disjoint),
// so intra-tile phase barriers are unnecessary. vmcnt(0) at tile end waits for
// loads issued a full tile (~1000 cyc) earlier -> cheap. Compiler inserts the
// counted lgkmcnt interleave between ds_reads and MFMAs (m97-verified).
__global__ __launch_bounds__(512, 1)
void gemm8_qkv(const ushort* __restrict__ A, const ushort* __restrict__ Bt,
               ushort* __restrict__ Qb, ushort* __restrict__ Kb, ushort* __restrict__ Vb)
{
  constexpr int K = 2048;
  constexpr int NT = K / 64;     // 32 K-tiles
  __shared__ char smem[131072];  // buf<<16 | {A:0, B:32768} ; [256][64] bf16, bit5^=row-bit2

  const int tid = threadIdx.x, wave = tid >> 6, lane = tid & 63;
  const int lr = lane & 15, lg = lane >> 4;
  const int wm = wave >> 2, wn = wave & 3;

  // XCD-aware 8x6 chunking (r3: FETCH 176->90 MB, keep)
  const int wg = blockIdx.x;            // 0..383
  const int xcd = wg & 7, l = wg >> 3;  // l in 0..47
  const int rgrp = xcd >> 2, cgrp = xcd & 3;
  const int lrow = l & 7, lcol = l >> 3;
  const int by = rgrp * 8 + lrow, bx = cgrp * 6 + lcol;
  const int m0 = by * 256, n0 = bx * 256;

  // precomputed swizzled fragment byte-offsets (add kk*64 at use; bit6 untouched by XOR)
  int offA[8], offB[4];
  #pragma unroll
  for (int mf = 0; mf < 8; ++mf) {
    const int r = wm * 128 + mf * 16 + lr;
    offA[mf] = r * 128 + ((lg * 16) ^ (((r >> 2) & 1) << 5));
  }
  #pragma unroll
  for (int nf = 0; nf < 4; ++nf) {
    const int r = wn * 64 + nf * 16 + lr;
    offB[nf] = r * 128 + ((lg * 16) ^ (((r >> 2) & 1) << 5));
  }

  // stage a full 256x64 A-tile and B-tile for K-tile U into buffer bufsel
  auto stage = [&](int U, int bufsel) {
    char* baseA = smem + (bufsel << 16);
    char* baseB = baseA + 32768;
    #pragma unroll
    for (int inst = 0; inst < 4; ++inst) {
      const int c = inst * 512 + tid;          // 16B chunk, lds off = c*16
      const int row = c >> 3;                  // 0..255
      const int colb = (c & 7) * 16;           // 0..112
      const int colsw = colb ^ (((row >> 2) & 1) << 5);  // inverse-swizzled SOURCE
      GLDS16(A  + (size_t)(m0 + row) * K + U * 64 + (colsw >> 1), baseA + inst * 8192 + wave * 1024);
    }
    #pragma unroll
    for (int inst = 0; inst < 4; ++inst) {
      const int c = inst * 512 + tid;
      const int row = c >> 3;
      const int colb = (c & 7) * 16;
      const int colsw = colb ^ (((row >> 2) & 1) << 5);
      GLDS16(Bt + (size_t)(n0 + row) * K + U * 64 + (colsw >> 1), baseB + inst * 8192 + wave * 1024);
    }
  };

  f32x4 acc[8][4] = {};

  stage(0, 0);
  asm volatile("s_waitcnt vmcnt(0)" ::: "memory");
  __builtin_amdgcn_s_barrier();

  for (int T = 0; T < NT; ++T) {
    const int buf = T & 1;
    if (T + 1 < NT) stage(T + 1, buf ^ 1);
    const char* Ab = smem + (buf << 16);
    const char* Bb = Ab + 32768;
    #pragma unroll
    for (int kk = 0; kk < 2; ++kk) {
      s16x8 af[8], bf[4];
      #pragma unroll
      for (int mf = 0; mf < 8; ++mf) af[mf] = *(const s16x8*)(Ab + kk * 64 + offA[mf]);
      #pragma unroll
      for (int nf = 0; nf < 4; ++nf) bf[nf] = *(const s16x8*)(Bb + kk * 64 + offB[nf]);
      __builtin_amdgcn_s_setprio(1);
      #pragma unroll
      for (int mf = 0; mf < 8; ++mf)
        #pragma unroll
        for (int nf = 0; nf < 4; ++nf)
          acc[mf][nf] = __builtin_amdgcn_mfma_f32_16x16x32_bf16(af[mf], bf[nf], acc[mf][nf], 0, 0, 0);
      __builtin_amdgcn_s_setprio(0);
    }
    asm volatile("s_waitcnt vmcnt(0) lgkmcnt(0)" ::: "memory");
    __builtin_amdgcn_s_barrier();
  }

  // epilogue: scatter bf16 into per-head Q/K/V [B,H,T,HD]
  #pragma unroll
  for (int mf = 0; mf < 8; ++mf) {
    #pragma unroll
    for (int nn = 0; nn < 4; ++nn) {
      #pragma unroll
      for (int r = 0; r < 4; ++r) {
        const int rowg = m0 + wm * 128 + mf * 16 + lg * 4 + r;
        const int colg = n0 + wn * 64 + nn * 16 + lr;
        const int which = colg >> 11, rem = colg & 2047;
        const int hh = rem >> 7, d = rem & 127;
        const int b2 = rowg >> 11, t = rowg & 2047;
        ushort* dstp = (which == 0) ? Qb : (which == 1) ? Kb : Vb;
        dstp[(((size_t)b2 * HH + hh) * TT + t) * HDIM + d] = f2bf(acc[mf][nn][r]);
      }
    }
  }
}

// ---------------- m97-style GEMM kept for the out-projection ----------------
__global__ __launch_bounds__(256, 2)
void gemm_bt2(const ushort* __restrict__ A, const ushort* __restrict__ Bt,
              float* __restrict__ Cf, int M, int N, int K)
{
  __shared__ ushort As[128 * 32];
  __shared__ ushort Bs[128 * 32];
  const int tid = threadIdx.x;
  const int wave = tid >> 6, lane = tid & 63;
  const int lr = lane & 15, lg = lane >> 4;
  const int m0 = blockIdx.y * 128, n0 = blockIdx.x * 128;
  const int wm = (wave & 1) * 64, wn = (wave >> 1) * 64;
  f32x4 acc[4][4] = {};

  for (int k0 = 0; k0 < K; k0 += 32) {
    __syncthreads();
    #pragma unroll
    for (int call = 0; call < 2; ++call) {
      const int base = call * 256 + wave * 64;
      const int c = base + lane;
      const int row = c >> 2, cc = c & 3;
      GLDS16(A  + (size_t)(m0 + row) * K + k0 + cc * 8, As + (size_t)base * 8);
      GLDS16(Bt + (size_t)(n0 + row) * K + k0 + cc * 8, Bs + (size_t)base * 8);
    }
    __syncthreads();
    s16x8 a[4], b[4];
    #pragma unroll
    for (int i = 0; i < 4; ++i) a[i] = *(const s16x8*)&As[(wm + i * 16 + lr) * 32 + lg * 8];
    #pragma unroll
    for (int i = 0; i < 4; ++i) b[i] = *(const s16x8*)&Bs[(wn + i * 16 + lr) * 32 + lg * 8];
    #pragma unroll
    for (int mi = 0; mi < 4; ++mi)
      #pragma unroll
      for (int ni = 0; ni < 4; ++ni)
        acc[mi][ni] = __builtin_amdgcn_mfma_f32_16x16x32_bf16(a[mi], b[ni], acc[mi][ni], 0, 0, 0);
  }

  #pragma unroll
  for (int mi = 0; mi < 4; ++mi)
    #pragma unroll
    for (int ni = 0; ni < 4; ++ni)
      #pragma unroll
      for (int r = 0; r < 4; ++r) {
        const int row = m0 + wm + mi * 16 + lg * 4 + r;
        const int col = n0 + wn + ni * 16 + lr;
        Cf[(size_t)row * N + col] = acc[mi][ni][r];
      }
}

// ---------------- in-place RoPE on Q and K ([B,H,T,HD] bf16) ----------------
__global__ void rope_inplace(ushort* __restrict__ Qb, ushort* __restrict__ Kb,
                             const float* __restrict__ sinp, const float* __restrict__ cosp) {
  const int idx = blockIdx.x * 256 + threadIdx.x;   // B*H*T*64 threads
  const int d = idx & 63;
  const int t = (idx >> 6) & (TT - 1);
  const int bh = idx >> 17;
  const float c = cosp[t * HDIM + d];
  const float s = sinp[t * HDIM + d];
  const size_t base = ((size_t)bh * TT + t) * HDIM + d;
  float q1 = bf2f(Qb[base]), q2 = bf2f(Qb[base + 64]);
  Qb[base]      = f2bf(q1 * c - q2 * s);
  Qb[base + 64] = f2bf(q2 * c + q1 * s);
  float k1 = bf2f(Kb[base]), k2 = bf2f(Kb[base + 64]);
  Kb[base]      = f2bf(k1 * c - k2 * s);
  Kb[base + 64] = f2bf(k2 * c + k1 * s);
}

// ---------------- flash attention with causal + same-doc mask ----------------
__global__ __launch_bounds__(256, 2)
void attn_kernel(const ushort* __restrict__ Qb, const ushort* __restrict__ Kb,
                 const ushort* __restrict__ Vb, const int* __restrict__ doc,
                 ushort* __restrict__ Ob)
{
  __shared__ ushort Ks[64 * 128];    // K tile, XOR-swizzled rows
  __shared__ ushort VTs[128 * 64];   // V^T tile, XOR-swizzled rows
  __shared__ ushort Ps[4][16 * 64];  // per-wave P tile, XOR-swizzled rows
  const int qt = blockIdx.x, h = blockIdx.y, b = blockIdx.z;
  const int q0 = qt * 64;
  const int tid = threadIdx.x, wave = tid >> 6, lane = tid & 63;
  const int lr = lane & 15, lg = lane >> 4;
  const size_t bh = (size_t)b * HH + h;
  const int* docb = doc + b * TT;

  const ushort* Qp = Qb + (bh * TT + q0 + wave * 16) * HDIM;
  s16x8 aq[4];
  #pragma unroll
  for (int ks = 0; ks < 4; ++ks) aq[ks] = *(const s16x8*)&Qp[lr * HDIM + ks * 32 + lg * 8];

  int qdoc[4];
  #pragma unroll
  for (int r = 0; r < 4; ++r) qdoc[r] = docb[q0 + wave * 16 + lg * 4 + r];
  const int qdoc0 = docb[q0];

  float m2[4], lsum[4];
  #pragma unroll
  for (int r = 0; r < 4; ++r) { m2[r] = -1e30f; lsum[r] = 0.f; }
  f32x4 oacc[8] = {};

  const float sc = 0.08838834764831843f * 1.4426950408889634f;  // 1/sqrt(128) * log2(e)

  const ushort* Kbase = Kb + bh * TT * HDIM;
  const ushort* Vbase = Vb + bh * TT * HDIM;

  const int ntiles = qt + 1;
  for (int kt = 0; kt < ntiles; ++kt) {
    const int kv0 = kt * 64;
    if (docb[kv0 + 63] < qdoc0) continue;
    __syncthreads();
    #pragma unroll
    for (int i = 0; i < 4; ++i) {
      const int c = tid + i * 256;
      const int row = c >> 4, c8 = c & 15;
      s16x8 v = *(const s16x8*)&Kbase[(size_t)(kv0 + row) * HDIM + c8 * 8];
      const int off = (row * 256 + c8 * 16) ^ ((row & 7) << 4);
      *(s16x8*)((char*)Ks + off) = v;
    }
    #pragma unroll
    for (int i = 0; i < 4; ++i) {
      const int c = tid + i * 256;
      const int kv = c >> 4, d8 = c & 15;
      s16x8 v = *(const s16x8*)&Vbase[(size_t)(kv0 + kv) * HDIM + d8 * 8];
      #pragma unroll
      for (int j = 0; j < 8; ++j) {
        const int d = d8 * 8 + j;
        const int off = (d * 128 + kv * 2) ^ ((d & 7) << 4);
        *(ushort*)((char*)VTs + off) = (ushort)v[j];
      }
    }
    __syncthreads();

    f32x4 sfrag[4] = {};
    #pragma unroll
    for (int ks = 0; ks < 4; ++ks) {
      #pragma unroll
      for (int ct = 0; ct < 4; ++ct) {
        const int row = ct * 16 + lr;
        const int off = (row * 256 + ks * 64 + lg * 16) ^ ((row & 7) << 4);
        s16x8 bk = *(const s16x8*)((char*)Ks + off);
        sfrag[ct] = __builtin_amdgcn_mfma_f32_16x16x32_bf16(aq[ks], bk, sfrag[ct], 0, 0, 0);
      }
    }

    int kd[4];
    #pragma unroll
    for (int ct = 0; ct < 4; ++ct) kd[ct] = docb[kv0 + ct * 16 + lr];

    float s[4][4], tmax[4];
    #pragma unroll
    for (int r = 0; r < 4; ++r) tmax[r] = -1e30f;
    #pragma unroll
    for (int ct = 0; ct < 4; ++ct) {
      const int col = kv0 + ct * 16 + lr;
      #pragma unroll
      for (int r = 0; r < 4; ++r) {
        const int row = q0 + wave * 16 + lg * 4 + r;
        float v = sfrag[ct][r] * sc;
        const bool keep = (col <= row) && (kd[ct] == qdoc[r]);
        v = keep ? v : -1e30f;
        s[ct][r] = v;
        tmax[r] = fmaxf(tmax[r], v);
      }
    }
    #pragma unroll
    for (int r = 0; r < 4; ++r) {
      #pragma unroll
      for (int off = 8; off >= 1; off >>= 1)
        tmax[r] = fmaxf(tmax[r], __shfl_xor(tmax[r], off, 16));
    }
    float alpha[4];
    #pragma unroll
    for (int r = 0; r < 4; ++r) {
      const float mnew = fmaxf(m2[r], tmax[r]);
      alpha[r] = exp2f(m2[r] - mnew);
      m2[r] = mnew;
      lsum[r] *= alpha[r];
    }
    #pragma unroll
    for (int ct = 0; ct < 4; ++ct) {
      #pragma unroll
      for (int r = 0; r < 4; ++r) {
        const float p = (s[ct][r] > -1e29f) ? exp2f(s[ct][r] - m2[r]) : 0.f;
        lsum[r] += p;
        const int prow = lg * 4 + r;
        const int off = (prow * 128 + (ct * 16 + lr) * 2) ^ ((prow & 7) << 4);
        *(ushort*)((char*)&Ps[wave][0] + off) = f2bf(p);
      }
    }
    #pragma unroll
    for (int oc = 0; oc < 8; ++oc)
      #pragma unroll
      for (int r = 0; r < 4; ++r) oacc[oc][r] *= alpha[r];
    #pragma unroll
    for (int ks = 0; ks < 2; ++ks) {
      const int poff = (lr * 128 + ks * 64 + lg * 16) ^ ((lr & 7) << 4);
      s16x8 ap = *(const s16x8*)((char*)&Ps[wave][0] + poff);
      #pragma unroll
      for (int oc = 0; oc < 8; ++oc) {
        const int vrow = oc * 16 + lr;
        const int voff = (vrow * 128 + ks * 64 + lg * 16) ^ ((vrow & 7) << 4);
        s16x8 bv = *(const s16x8*)((char*)VTs + voff);
        oacc[oc] = __builtin_amdgcn_mfma_f32_16x16x32_bf16(ap, bv, oacc[oc], 0, 0, 0);
      }
    }
  }

  #pragma unroll
  for (int r = 0; r < 4; ++r)
    #pragma unroll
    for (int off = 8; off >= 1; off >>= 1)
      lsum[r] += __shfl_xor(lsum[r], off, 16);

  ushort* Op = Ob + ((size_t)b * TT + q0 + wave * 16) * DD + (size_t)h * HDIM;
  #pragma unroll
  for (int oc = 0; oc < 8; ++oc)
    #pragma unroll
    for (int r = 0; r < 4; ++r)
      Op[(lg * 4 + r) * DD + oc * 16 + lr] = f2bf(oacc[oc][r] / lsum[r]);
}

extern "C" void kernel_launch(void* const* d_in, const int* in_sizes, int n_in,
                              void* d_out, int out_size, void* d_ws, size_t ws_size,
                              hipStream_t stream)
{
  const float* x    = (const float*)d_in[0];
  const float* sinp = (const float*)d_in[1];
  const float* cosp = (const float*)d_in[2];
  const float* Wqkv = (const float*)d_in[3];
  const float* Wout = (const float*)d_in[4];
  const int*   doc  = (const int*)d_in[5];
  float* out = (float*)d_out;

  ushort* xb  = (ushort*)d_ws;                     // 4096*2048 bf16
  ushort* WqT = xb  + (size_t)BT * DD;             // 6144*2048
  ushort* WoT = WqT + (size_t)N3 * DD;             // 2048*2048
  ushort* Qb  = WoT + (size_t)DD * DD;             // [B,H,T,HD]
  ushort* Kb  = Qb  + (size_t)BB * TT * DD;
  ushort* Vb  = Kb  + (size_t)BB * TT * DD;
  ushort* Ob  = Vb  + (size_t)BB * TT * DD;        // [B,T,D]

  cvt_kernel<<<(BT * DD / 4 + 255) / 256, 256, 0, stream>>>(x, xb, BT * DD / 4);
  transpose_cvt<<<dim3(N3 / 32, DD / 32), dim3(32, 8), 0, stream>>>(Wqkv, WqT, DD, N3);
  transpose_cvt<<<dim3(DD / 32, DD / 32), dim3(32, 8), 0, stream>>>(Wout, WoT, DD, DD);
  gemm8_qkv<<<dim3((N3 / 256) * (BT / 256)), 512, 0, stream>>>(xb, WqT, Qb, Kb, Vb);
  rope_inplace<<<BB * HH * TT * 64 / 256, 256, 0, stream>>>(Qb, Kb, sinp, cosp);
  attn_kernel<<<dim3(TT / 64, HH, BB), 256, 0, stream>>>(Qb, Kb, Vb, doc, Ob);
  gemm_bt2<<<dim3(DD / 128, BT / 128), 256, 0, stream>>>(Ob, WoT, out, BT, DD, DD);
}